// Round 5
// baseline (245.814 us; speedup 1.0000x reference)
//
#include <hip/hip_runtime.h>
#include <hip/hip_bf16.h>
#include <math.h>

typedef short short8 __attribute__((ext_vector_type(8)));
typedef float f32x16 __attribute__((ext_vector_type(16)));

#define BB 16
#define CC 256
#define HH 64
#define WW 64
#define HWX 4096
#define DD 4
#define KD 9
#define KK 81

__device__ __forceinline__ short bf16c(float x) {
    __hip_bfloat16 h = __float2bfloat16(x);
    return *reinterpret_cast<short*>(&h);
}

__global__ __launch_bounds__(256) void corr_mfma(
    const float* __restrict__ fA, const float* __restrict__ fB,
    float* __restrict__ out)
{
    __shared__ __attribute__((aligned(16))) unsigned short Abf[WW * CC]; // 32 KB bf16 A (invA folded)
    __shared__ float red[KD][WW + 1];     // +1 pad: scatter bank = (dx+w)%32, conflict-free
    __shared__ float part[4 * WW];
    __shared__ float invA_ls[WW];

    // XCD-aware swizzle: 1024 blocks, 8 XCDs (1024 % 8 == 0 -> bijective)
    const int bid = blockIdx.x;
    const int swz = (bid & 7) * 128 + (bid >> 3);
    const int b = swz >> 6, h = swz & 63;

    const int tid = threadIdx.x;
    const int wv = tid >> 6, l = tid & 63;
    const int ti = wv >> 1, tj = wv & 1;     // wave quadrant of the 64x64 gram
    const int ml = l & 31, kg = l >> 5;
    const int m = ti * 32 + ml;              // A row (w)
    const int n = tj * 32 + ml;              // B row (w')

    const float* Abase = fA + (size_t)b * CC * HWX + h * WW;

    // ---- prologue pass 1: raw A sumsq -> invA ----
    {
        float ss = 0.f;
        #pragma unroll
        for (int r = 0; r < 8; ++r) {
            float v[8];
            #pragma unroll
            for (int j = 0; j < 8; ++j) v[j] = Abase[(size_t)(wv * 64 + r * 8 + j) * HWX + l];
            #pragma unroll
            for (int j = 0; j < 8; ++j) ss += v[j] * v[j];
        }
        part[wv * 64 + l] = ss;
    }
    __syncthreads();
    if (tid < WW) {
        float s = part[tid] + part[64 + tid] + part[128 + tid] + part[192 + tid];
        invA_ls[tid] = 1.f / fmaxf(sqrtf(s), 1e-12f);
    }
    __syncthreads();

    // ---- prologue pass 2: reload (L2-hot), scale by invA, cvt, stage bf16 ----
    {
        const float ia = invA_ls[l];
        #pragma unroll
        for (int r = 0; r < 8; ++r) {
            const int c = wv * 64 + r * 8;
            float v[8]; short8 st;
            #pragma unroll
            for (int j = 0; j < 8; ++j) v[j] = Abase[(size_t)(c + j) * HWX + l];
            #pragma unroll
            for (int j = 0; j < 8; ++j) st[j] = bf16c(v[j] * ia);
            const int byte = (l * 512 + c * 2) ^ ((l & 31) << 4);
            *(short8*)((char*)Abf + byte) = st;
        }
    }
    // zero red (incl. pad); band-edge entries stay zero forever
    for (int i = tid; i < KD * (WW + 1); i += 256) ((float*)red)[i] = 0.f;
    __syncthreads();

    // hoist A fragments (A-region is never rewritten; no barrier needed after)
    short8 afr[16];
    #pragma unroll
    for (int s = 0; s < 16; ++s) {
        const int byte = (m * 512 + s * 32 + kg * 16) ^ ((m & 31) << 4);
        afr[s] = *(const short8*)((const char*)Abf + byte);
    }

    // ---- dy loop: B-frags straight from global, barrier-free contraction ----
    const float* fBb = fB + (size_t)b * CC * HWX;
    for (int dy = 0; dy < KD; ++dy) {
        const int hB = h + dy - DD;
        float* obase = out + (((size_t)b * KK + dy * KD) * HH + h) * WW;
        if ((unsigned)hB < HH) {                        // block-uniform branch
            const float* pB = fBb + (size_t)hB * WW + n + (size_t)kg * 8 * HWX;
            f32x16 acc;
            #pragma unroll
            for (int i = 0; i < 16; ++i) acc[i] = 0.f;
            float s0 = 0.f, s1 = 0.f, s2 = 0.f, s3 = 0.f;
            #pragma unroll
            for (int s = 0; s < 16; ++s) {
                float v[8]; short8 bfr;
                #pragma unroll
                for (int j = 0; j < 8; ++j) v[j] = pB[(size_t)(s * 16 + j) * HWX];
                s0 += v[0] * v[0]; s1 += v[1] * v[1];
                s2 += v[2] * v[2]; s3 += v[3] * v[3];
                s0 += v[4] * v[4]; s1 += v[5] * v[5];
                s2 += v[6] * v[6]; s3 += v[7] * v[7];
                #pragma unroll
                for (int j = 0; j < 8; ++j) bfr[j] = bf16c(v[j]);
                acc = __builtin_amdgcn_mfma_f32_32x32x16_bf16(afr[s], bfr, acc, 0, 0, 0);
            }
            // per-lane invB at row n: own 128-c partial + kg-partner half
            float ssl = (s0 + s1) + (s2 + s3);
            ssl += __shfl_xor(ssl, 32, 64);
            const float ibn = 1.f / fmaxf(sqrtf(ssl), 1e-12f);
            // band scatter (invA already folded into A)
            #pragma unroll
            for (int r = 0; r < 16; ++r) {
                // D layout (m74/m101): col = lane&31 (=w'), row = (r&3)+8*(r>>2)+4*kg
                const int w = ti * 32 + (r & 3) + 8 * (r >> 2) + 4 * kg;
                const int dx = n - w + 4;
                if (dx >= 0 && dx < KD)
                    red[dx][w] = acc[r] * ibn;
            }
            __syncthreads();                 // red complete
            for (int i = tid; i < KD * WW; i += 256)
                obase[(size_t)(i >> 6) * HWX + (i & 63)] = red[i >> 6][i & 63];
            __syncthreads();                 // red reads done before next scatter
        } else {
            // whole dy-plane is zero padding; out is poisoned so must write
            for (int i = tid; i < KD * WW; i += 256)
                obase[(size_t)(i >> 6) * HWX + (i & 63)] = 0.f;
        }
    }
}

extern "C" void kernel_launch(void* const* d_in, const int* in_sizes, int n_in,
                              void* d_out, int out_size, void* d_ws, size_t ws_size,
                              hipStream_t stream) {
    const float* fA = (const float*)d_in[0];
    const float* fB = (const float*)d_in[1];
    float* outp = (float*)d_out;
    corr_mfma<<<dim3(BB * HH), 256, 0, stream>>>(fA, fB, outp);
}

// Round 6
// 167.948 us; speedup vs baseline: 1.4636x; 1.4636x over previous
//
#include <hip/hip_runtime.h>
#include <hip/hip_bf16.h>
#include <math.h>

typedef short short8 __attribute__((ext_vector_type(8)));
typedef float f32x16 __attribute__((ext_vector_type(16)));

#define BB 16
#define CC 256
#define HH 64
#define WW 64
#define HWX 4096
#define DD 4
#define KD 9
#define KK 81
#define NSLOT 10

__device__ __forceinline__ short bf16c(float x) {
    __hip_bfloat16 h = __float2bfloat16(x);
    return *reinterpret_cast<short*>(&h);
}

// issue 32 strided global loads for one B row chunk (lane: w=l, c=wv*32..+31)
__device__ __forceinline__ void b_issue(const float* __restrict__ row,
                                        int wv, int l, float* v) {
    #pragma unroll
    for (int j = 0; j < 32; ++j)
        v[j] = row[(size_t)(wv * 32 + j) * HWX + l];
}

// cvt + swizzled LDS write + fp32 sumsq partial
__device__ __forceinline__ void b_commit(const float* v, unsigned short* bufp,
                                         float* partp, int wv, int l) {
    float ss = 0.f;
    #pragma unroll
    for (int j = 0; j < 32; ++j) ss += v[j] * v[j];
    #pragma unroll
    for (int ch = 0; ch < 4; ++ch) {
        short8 st;
        #pragma unroll
        for (int j = 0; j < 8; ++j) st[j] = bf16c(v[ch * 8 + j]);
        const int c = wv * 32 + ch * 8;
        const int byte = (l * 512 + c * 2) ^ ((l & 31) << 4);
        *(short8*)((char*)bufp + byte) = st;
    }
    partp[wv * 64 + l] = ss;
}

__global__ __launch_bounds__(512, 4) void corr_mfma(
    const float* __restrict__ fA, const float* __restrict__ fB,
    float* __restrict__ out)
{
    __shared__ __attribute__((aligned(16))) unsigned short buf[2][WW * CC]; // 64 KB
    __shared__ float red[2][2][KD][WW + 1];   // [group][parity], padded scatter
    __shared__ float part[2][8 * WW];         // [parity] sumsq partials (part[1] doubles as A partials)

    const int bid = blockIdx.x;                       // 512 blocks
    const int swzb = (bid & 7) * 64 + (bid >> 3);     // XCD-bijective (512%8==0)
    const int b = swzb >> 5, jr = swzb & 31;
    const int h0 = 2 * jr;

    const int tid = threadIdx.x;
    const int wv = tid >> 6, l = tid & 63;
    const int g = wv >> 2;                 // group: row h0+g
    const int q = wv & 3;                  // quadrant wave within group
    const int hg = h0 + g;
    const int ti = q >> 1, tj = q & 1;
    const int ml = l & 31, kg = l >> 5;
    const int m = ti * 32 + ml;            // A row (w)
    const int n = tj * 32 + ml;            // B row (w')

    // ---- A prologue (two-pass: sumsq, then invA-folded bf16 stage) ----
    const float* Abase = fA + (size_t)b * CC * HWX + hg * WW;
    {
        float ss = 0.f;
        #pragma unroll
        for (int r = 0; r < 8; ++r) {
            float v[8];
            #pragma unroll
            for (int j = 0; j < 8; ++j) v[j] = Abase[(size_t)(q * 64 + r * 8 + j) * HWX + l];
            #pragma unroll
            for (int j = 0; j < 8; ++j) ss += v[j] * v[j];
        }
        part[1][wv * 64 + l] = ss;     // partA aliases part[1] (rewritten later)
    }
    __syncthreads();
    float iaA;
    {
        float s = part[1][(g * 4 + 0) * 64 + l] + part[1][(g * 4 + 1) * 64 + l]
                + part[1][(g * 4 + 2) * 64 + l] + part[1][(g * 4 + 3) * 64 + l];
        iaA = 1.f / fmaxf(sqrtf(s), 1e-12f);
    }
    for (int i = tid; i < 2 * 2 * KD * (WW + 1); i += 512) ((float*)red)[i] = 0.f;
    #pragma unroll
    for (int r = 0; r < 8; ++r) {
        const int c = q * 64 + r * 8;
        float v[8]; short8 st;
        #pragma unroll
        for (int j = 0; j < 8; ++j) v[j] = Abase[(size_t)(c + j) * HWX + l];
        #pragma unroll
        for (int j = 0; j < 8; ++j) st[j] = bf16c(v[j] * iaA);
        const int byte = (l * 512 + c * 2) ^ ((l & 31) << 4);
        *(short8*)((char*)buf[g] + byte) = st;
    }
    __syncthreads();
    short8 afr[16];
    #pragma unroll
    for (int s = 0; s < 16; ++s) {
        const int byte = (m * 512 + s * 32 + kg * 16) ^ ((m & 31) << 4);
        afr[s] = *(const short8*)((const char*)buf[g] + byte);
    }
    __syncthreads();      // hoist reads complete before buf[0] is restaged

    // ---- B pipeline: 10 shared row-slots, ONE barrier per slot ----
    const float* fBb = fB + (size_t)b * CC * HWX;
    {   // prologue: stage slot 0 into buf[0]
        const int hb0 = h0 - DD;
        if ((unsigned)hb0 < HH) {
            float v[32];
            b_issue(fBb + (size_t)hb0 * WW, wv, l, v);
            b_commit(v, buf[0], part[0], wv, l);
        }
    }
    __syncthreads();

    for (int r = 0; r < NSLOT; ++r) {
        const int cur = r & 1;
        const int hb = h0 - DD + r;
        const bool vcur = (unsigned)hb < HH;
        // 1. store previous slot's red (parity cur^1; no conflict with this slot)
        if (r >= 1) {
            const int dyp = (r - 1) - g;
            if (dyp >= 0 && dyp < KD) {
                const int tid2 = q * 64 + l;
                float* ob = out + (((size_t)b * KK + dyp * KD) * HH + hg) * WW;
                for (int i = tid2; i < KD * WW; i += 256)
                    ob[(size_t)(i >> 6) * HWX + (i & 63)] = red[g][cur ^ 1][i >> 6][i & 63];
            }
        }
        // 2. issue next slot's loads (fly under MFMA)
        float v[32];
        const bool vnext = (r + 1 < NSLOT) && ((unsigned)(hb + 1) < HH);
        if (vnext) b_issue(fBb + (size_t)(hb + 1) * WW, wv, l, v);
        // 3. compute this slot
        const int dy = r - g;
        if (dy >= 0 && dy < KD) {
            if (vcur) {
                f32x16 acc;
                #pragma unroll
                for (int i = 0; i < 16; ++i) acc[i] = 0.f;
                #pragma unroll
                for (int s = 0; s < 16; ++s) {
                    const int byte = (n * 512 + s * 32 + kg * 16) ^ ((n & 31) << 4);
                    short8 bfr = *(const short8*)((const char*)buf[cur] + byte);
                    acc = __builtin_amdgcn_mfma_f32_32x32x16_bf16(afr[s], bfr, acc, 0, 0, 0);
                }
                float sB = 0.f;
                #pragma unroll
                for (int qq = 0; qq < 8; ++qq) sB += part[cur][qq * 64 + n];
                const float ibn = 1.f / fmaxf(sqrtf(sB), 1e-12f);
                #pragma unroll
                for (int rr = 0; rr < 16; ++rr) {
                    // D layout (m74/m101): col = lane&31 (=w'), row = (rr&3)+8*(rr>>2)+4*kg
                    const int w = ti * 32 + (rr & 3) + 8 * (rr >> 2) + 4 * kg;
                    const int dx = n - w + 4;
                    if (dx >= 0 && dx < KD) red[g][cur][dx][w] = acc[rr] * ibn;
                }
            } else {
                #pragma unroll
                for (int rr = 0; rr < 16; ++rr) {
                    const int w = ti * 32 + (rr & 3) + 8 * (rr >> 2) + 4 * kg;
                    const int dx = n - w + 4;
                    if (dx >= 0 && dx < KD) red[g][cur][dx][w] = 0.f;
                }
            }
        }
        // 4. commit staged row to buf[cur^1] (vmcnt wait happens here, after MFMA)
        if (vnext) b_commit(v, buf[cur ^ 1], part[cur ^ 1], wv, l);
        __syncthreads();
    }
    // final store for slot NSLOT-1
    {
        const int dyp = (NSLOT - 1) - g;
        if (dyp >= 0 && dyp < KD) {
            const int tid2 = q * 64 + l;
            float* ob = out + (((size_t)b * KK + dyp * KD) * HH + hg) * WW;
            for (int i = tid2; i < KD * WW; i += 256)
                ob[(size_t)(i >> 6) * HWX + (i & 63)] = red[g][(NSLOT - 1) & 1][i >> 6][i & 63];
        }
    }
}

extern "C" void kernel_launch(void* const* d_in, const int* in_sizes, int n_in,
                              void* d_out, int out_size, void* d_ws, size_t ws_size,
                              hipStream_t stream) {
    const float* fA = (const float*)d_in[0];
    const float* fB = (const float*)d_in[1];
    float* outp = (float*)d_out;
    corr_mfma<<<dim3(BB * HH / 2), 512, 0, stream>>>(fA, fB, outp);
}

// Round 7
// 64.933 us; speedup vs baseline: 3.7856x; 2.5865x over previous
//
#include <hip/hip_runtime.h>
#include <hip/hip_bf16.h>
#include <math.h>

typedef short short8 __attribute__((ext_vector_type(8)));
typedef float f32x16 __attribute__((ext_vector_type(16)));

#define BB 16
#define CC 256
#define HH 64
#define WW 64
#define HWX 4096
#define DD 4
#define KD 9
#define KK 81
#define NSLOT 10

__device__ __forceinline__ short bf16c(float x) {
    __hip_bfloat16 h = __float2bfloat16(x);
    return *reinterpret_cast<short*>(&h);
}

// issue 16 strided global loads (half a B row chunk): c = c0..c0+15 at w=l
__device__ __forceinline__ void b_issue16(const float* __restrict__ row,
                                          int c0, int l, float* v) {
    #pragma unroll
    for (int j = 0; j < 16; ++j)
        v[j] = row[(size_t)(c0 + j) * HWX + l];
}

// cvt + swizzled LDS write of 16 channels; returns sumsq partial
__device__ __forceinline__ float b_commit16(const float* v, unsigned short* bufp,
                                            int c0, int l) {
    float ss = 0.f;
    #pragma unroll
    for (int j = 0; j < 16; ++j) ss += v[j] * v[j];
    #pragma unroll
    for (int ch = 0; ch < 2; ++ch) {
        short8 st;
        #pragma unroll
        for (int j = 0; j < 8; ++j) st[j] = bf16c(v[ch * 8 + j]);
        const int c = c0 + ch * 8;
        const int byte = (l * 512 + c * 2) ^ ((l & 31) << 4);
        *(short8*)((char*)bufp + byte) = st;
    }
    return ss;
}

__global__ __launch_bounds__(512) void corr_mfma(
    const float* __restrict__ fA, const float* __restrict__ fB,
    float* __restrict__ out)
{
    __shared__ __attribute__((aligned(16))) unsigned short buf[2][WW * CC]; // 64 KB
    __shared__ float red[2][2][KD][WW + 1];   // [group][parity], padded scatter
    __shared__ float part[2][8 * WW];         // [parity] sumsq partials (part[1] doubles as A partials)

    const int bid = blockIdx.x;                       // 512 blocks
    const int swzb = (bid & 7) * 64 + (bid >> 3);     // XCD-bijective (512%8==0)
    const int b = swzb >> 5, jr = swzb & 31;
    const int h0 = 2 * jr;

    const int tid = threadIdx.x;
    const int wv = tid >> 6, l = tid & 63;
    const int g = wv >> 2;                 // group: row h0+g
    const int q = wv & 3;                  // quadrant wave within group
    const int hg = h0 + g;
    const int ti = q >> 1, tj = q & 1;
    const int ml = l & 31, kg = l >> 5;
    const int m = ti * 32 + ml;            // A row (w)
    const int n = tj * 32 + ml;            // B row (w')

    // ---- A prologue (two-pass: sumsq, then invA-folded bf16 stage) ----
    const float* Abase = fA + (size_t)b * CC * HWX + hg * WW;
    {
        float ss = 0.f;
        #pragma unroll
        for (int r = 0; r < 8; ++r) {
            float v[8];
            #pragma unroll
            for (int j = 0; j < 8; ++j) v[j] = Abase[(size_t)(q * 64 + r * 8 + j) * HWX + l];
            #pragma unroll
            for (int j = 0; j < 8; ++j) ss += v[j] * v[j];
        }
        part[1][wv * 64 + l] = ss;     // partA aliases part[1] (rewritten later)
    }
    __syncthreads();
    float iaA;
    {
        float s = part[1][(g * 4 + 0) * 64 + l] + part[1][(g * 4 + 1) * 64 + l]
                + part[1][(g * 4 + 2) * 64 + l] + part[1][(g * 4 + 3) * 64 + l];
        iaA = 1.f / fmaxf(sqrtf(s), 1e-12f);
    }
    for (int i = tid; i < 2 * 2 * KD * (WW + 1); i += 512) ((float*)red)[i] = 0.f;
    #pragma unroll
    for (int r = 0; r < 8; ++r) {
        const int c = q * 64 + r * 8;
        float v[8]; short8 st;
        #pragma unroll
        for (int j = 0; j < 8; ++j) v[j] = Abase[(size_t)(c + j) * HWX + l];
        #pragma unroll
        for (int j = 0; j < 8; ++j) st[j] = bf16c(v[j] * iaA);
        const int byte = (l * 512 + c * 2) ^ ((l & 31) << 4);
        *(short8*)((char*)buf[g] + byte) = st;
    }
    __syncthreads();
    short8 afr[16];
    #pragma unroll
    for (int s = 0; s < 16; ++s) {
        const int byte = (m * 512 + s * 32 + kg * 16) ^ ((m & 31) << 4);
        afr[s] = *(const short8*)((const char*)buf[g] + byte);
    }
    __syncthreads();      // hoist reads complete before buf[0] is restaged

    // ---- B pipeline: 10 shared row-slots, ONE barrier per slot ----
    const float* fBb = fB + (size_t)b * CC * HWX;
    {   // prologue: stage slot 0 into buf[0] (two half-rows)
        const int hb0 = h0 - DD;
        if ((unsigned)hb0 < HH) {
            const float* row = fBb + (size_t)hb0 * WW;
            float v[16];
            b_issue16(row, wv * 32, l, v);
            float ss = b_commit16(v, buf[0], wv * 32, l);
            b_issue16(row, wv * 32 + 16, l, v);
            ss += b_commit16(v, buf[0], wv * 32 + 16, l);
            part[0][wv * 64 + l] = ss;
        }
    }
    __syncthreads();

    for (int r = 0; r < NSLOT; ++r) {
        const int cur = r & 1;
        const int hb = h0 - DD + r;
        const bool vcur = (unsigned)hb < HH;
        const bool vnext = (r + 1 < NSLOT) && ((unsigned)(hb + 1) < HH);
        const float* nrow = fBb + (size_t)(hb + 1) * WW;
        const int dy = r - g;
        const bool dyv = (dy >= 0 && dy < KD);

        // 1. issue half0 of next row (flies under prev-store + MFMA octet 1)
        float v[16];
        if (vnext) b_issue16(nrow, wv * 32, l, v);

        // 2. store previous slot's red (parity cur^1)
        if (r >= 1) {
            const int dyp = (r - 1) - g;
            if (dyp >= 0 && dyp < KD) {
                const int tid2 = q * 64 + l;
                float* ob = out + (((size_t)b * KK + dyp * KD) * HH + hg) * WW;
                for (int i = tid2; i < KD * WW; i += 256)
                    ob[(size_t)(i >> 6) * HWX + (i & 63)] = red[g][cur ^ 1][i >> 6][i & 63];
            }
        }

        // 3. MFMA octet 1
        f32x16 acc;
        const bool comp = dyv && vcur;
        if (comp) {
            #pragma unroll
            for (int i = 0; i < 16; ++i) acc[i] = 0.f;
            #pragma unroll
            for (int s = 0; s < 8; ++s) {
                const int byte = (n * 512 + s * 32 + kg * 16) ^ ((n & 31) << 4);
                short8 bfr = *(const short8*)((const char*)buf[cur] + byte);
                acc = __builtin_amdgcn_mfma_f32_32x32x16_bf16(afr[s], bfr, acc, 0, 0, 0);
            }
        }

        // 4. commit half0 (vmcnt covered by octet 1), issue half1
        float ssn = 0.f;
        if (vnext) {
            ssn = b_commit16(v, buf[cur ^ 1], wv * 32, l);
            b_issue16(nrow, wv * 32 + 16, l, v);
        }

        // 5. MFMA octet 2 + epilogue scatter
        if (comp) {
            #pragma unroll
            for (int s = 8; s < 16; ++s) {
                const int byte = (n * 512 + s * 32 + kg * 16) ^ ((n & 31) << 4);
                short8 bfr = *(const short8*)((const char*)buf[cur] + byte);
                acc = __builtin_amdgcn_mfma_f32_32x32x16_bf16(afr[s], bfr, acc, 0, 0, 0);
            }
            float sB = 0.f;
            #pragma unroll
            for (int qq = 0; qq < 8; ++qq) sB += part[cur][qq * 64 + n];
            const float ibn = 1.f / fmaxf(sqrtf(sB), 1e-12f);
            #pragma unroll
            for (int rr = 0; rr < 16; ++rr) {
                // D layout (m74/m101): col = lane&31 (=w'), row = (rr&3)+8*(rr>>2)+4*kg
                const int w = ti * 32 + (rr & 3) + 8 * (rr >> 2) + 4 * kg;
                const int dx = n - w + 4;
                if (dx >= 0 && dx < KD) red[g][cur][dx][w] = acc[rr] * ibn;
            }
        } else if (dyv) {
            #pragma unroll
            for (int rr = 0; rr < 16; ++rr) {
                const int w = ti * 32 + (rr & 3) + 8 * (rr >> 2) + 4 * kg;
                const int dx = n - w + 4;
                if (dx >= 0 && dx < KD) red[g][cur][dx][w] = 0.f;
            }
        }

        // 6. commit half1, write sumsq partial
        if (vnext) {
            ssn += b_commit16(v, buf[cur ^ 1], wv * 32 + 16, l);
            part[cur ^ 1][wv * 64 + l] = ssn;
        }
        __syncthreads();
    }

    // final store for slot NSLOT-1
    {
        const int dyp = (NSLOT - 1) - g;
        if (dyp >= 0 && dyp < KD) {
            const int tid2 = q * 64 + l;
            float* ob = out + (((size_t)b * KK + dyp * KD) * HH + hg) * WW;
            for (int i = tid2; i < KD * WW; i += 256)
                ob[(size_t)(i >> 6) * HWX + (i & 63)] = red[g][(NSLOT - 1) & 1][i >> 6][i & 63];
        }
    }
}

extern "C" void kernel_launch(void* const* d_in, const int* in_sizes, int n_in,
                              void* d_out, int out_size, void* d_ws, size_t ws_size,
                              hipStream_t stream) {
    const float* fA = (const float*)d_in[0];
    const float* fB = (const float*)d_in[1];
    float* outp = (float*)d_out;
    corr_mfma<<<dim3(BB * HH / 2), 512, 0, stream>>>(fA, fB, outp);
}